// Round 1
// baseline (418.376 us; speedup 1.0000x reference)
//
#include <hip/hip_runtime.h>
#include <stdint.h>

// Problem constants (match reference: B=64, D=8, N=2048, L=64)
#define B_ 64
#define D_ 8
#define N_ 2048
#define L_ 64

__device__ __forceinline__ bool is_ninf(float v) {
    // exact -inf bit pattern; immune to -ffast-math folding of inf compares
    return __float_as_uint(v) == 0xFF800000u;
}

// One wave (64 lanes) handles one (b,n): all D=8 rows of L=64 floats.
// Lane layout: g = lane>>4 selects row group (4 rows per float4-load step),
// c = lane&15 selects the float4 within the 64-float row.
__global__ __launch_bounds__(256) void imputer_kernel(const float* __restrict__ x,
                                                      float* __restrict__ out) {
    const int lane = threadIdx.x & 63;
    const int wave = threadIdx.x >> 6;
    const int p    = blockIdx.x * 4 + wave;      // (b,n) pair index, 0..B*N-1
    const int b    = p >> 11;                    // p / N_
    const int n    = p & (N_ - 1);               // p % N_

    const size_t rstride = (size_t)N_ * L_;      // stride between d-rows
    const size_t base    = (size_t)b * (D_ * rstride) + (size_t)n * L_;

    const int g = lane >> 4;                     // 0..3 (row within load step)
    const int c = lane & 15;                     // float4 index within row

    const float* p0 = x + base + (size_t)g       * rstride + (size_t)c * 4;
    const float* p1 = x + base + (size_t)(g + 4) * rstride + (size_t)c * 4;

    float4 v0 = *(const float4*)p0;              // rows 0..3
    float4 v1 = *(const float4*)p1;              // rows 4..7

    const bool m0x = is_ninf(v0.x), m0y = is_ninf(v0.y), m0z = is_ninf(v0.z), m0w = is_ninf(v0.w);
    const bool m1x = is_ninf(v1.x), m1y = is_ninf(v1.y), m1z = is_ninf(v1.z), m1w = is_ninf(v1.w);

    const unsigned long long bal0 = __ballot(m0x | m0y | m0z | m0w);
    const unsigned long long bal1 = __ballot(m1x | m1y | m1z | m1w);

    // rowmiss bit d set iff row d of this (b,n) has any -inf. Wave-uniform.
    unsigned mask8 = 0;
#pragma unroll
    for (int d = 0; d < 4; ++d) {
        if ((bal0 >> (16 * d)) & 0xFFFFull) mask8 |= 1u << d;
        if ((bal1 >> (16 * d)) & 0xFFFFull) mask8 |= 1u << (d + 4);
    }

    float mean = 0.0f;
    if (mask8) {  // wave-uniform branch (mask8 derived from ballots)
        const int d0 = __ffs(mask8) - 1;         // smallest d with a missing entry
        const int h0 = d0 >> 2;                  // which load step holds row d0
        const int g0 = d0 & 3;                   // which lane group holds row d0

        const float4 vv = h0 ? v1 : v0;
        float ps = 0.0f, pc = 0.0f;
        if (g == g0) {
            if (!is_ninf(vv.x)) { ps += vv.x; pc += 1.0f; }
            if (!is_ninf(vv.y)) { ps += vv.y; pc += 1.0f; }
            if (!is_ninf(vv.z)) { ps += vv.z; pc += 1.0f; }
            if (!is_ninf(vv.w)) { ps += vv.w; pc += 1.0f; }
        }
        // butterfly reduce across the full 64-lane wave
#pragma unroll
        for (int off = 32; off; off >>= 1) {
            ps += __shfl_xor(ps, off, 64);
            pc += __shfl_xor(pc, off, 64);
        }
        mean = (pc > 0.0f) ? (ps / pc) : 0.0f;   // all-missing row -> 0
    }

    v0.x = m0x ? mean : v0.x;
    v0.y = m0y ? mean : v0.y;
    v0.z = m0z ? mean : v0.z;
    v0.w = m0w ? mean : v0.w;
    v1.x = m1x ? mean : v1.x;
    v1.y = m1y ? mean : v1.y;
    v1.z = m1z ? mean : v1.z;
    v1.w = m1w ? mean : v1.w;

    float* q0 = out + base + (size_t)g       * rstride + (size_t)c * 4;
    float* q1 = out + base + (size_t)(g + 4) * rstride + (size_t)c * 4;
    *(float4*)q0 = v0;
    *(float4*)q1 = v1;
}

extern "C" void kernel_launch(void* const* d_in, const int* in_sizes, int n_in,
                              void* d_out, int out_size, void* d_ws, size_t ws_size,
                              hipStream_t stream) {
    const float* x = (const float*)d_in[0];
    float* out = (float*)d_out;
    const int pairs = B_ * N_;                   // 131072 (b,n) pairs
    const int blocks = pairs / 4;                // 4 waves per 256-thread block
    imputer_kernel<<<blocks, 256, 0, stream>>>(x, out);
}